// Round 1
// baseline (221.396 us; speedup 1.0000x reference)
//
#include <hip/hip_runtime.h>
#include <math.h>

#define VOCABN 6
#define DIM 32
#define PADI 5
#define BATCH 256
#define SEQ 4096
#define KSEL 614   // int(4096 * 0.15)

// ---------------------------------------------------------------------------
// Kernel A: per-vocab precompute (6 tiny MLPs) + stable rank of vocab by score
// ---------------------------------------------------------------------------
__global__ void precompute_kernel(const float* __restrict__ emb,
                                  const float* __restrict__ sel_w1, const float* __restrict__ sel_b1,
                                  const float* __restrict__ sel_w2, const float* __restrict__ sel_b2,
                                  const float* __restrict__ app_w1, const float* __restrict__ app_b1,
                                  const float* __restrict__ app_w2, const float* __restrict__ app_b2,
                                  float* __restrict__ ws_score, float* __restrict__ ws_a,
                                  int* __restrict__ ws_rank) {
    const int v = threadIdx.x;
    __shared__ float s_score[VOCABN];
    if (v < VOCABN) {
        float e[DIM];
        for (int d = 0; d < DIM; ++d) e[d] = (v == PADI) ? 0.f : emb[v * DIM + d];
        // selector: D -> D/2 -> 1, sigmoid
        float h[DIM / 2];
        for (int j = 0; j < DIM / 2; ++j) {
            float acc = sel_b1[j];
            for (int d = 0; d < DIM; ++d) acc += e[d] * sel_w1[d * (DIM / 2) + j];
            h[j] = fmaxf(acc, 0.f);
        }
        float z = sel_b2[0];
        for (int j = 0; j < DIM / 2; ++j) z += h[j] * sel_w2[j];
        const float sc = 1.f / (1.f + expf(-z));
        s_score[v] = sc;
        ws_score[v] = sc;
        // approximator: D -> D -> D
        float tt[DIM];
        for (int j = 0; j < DIM; ++j) {
            float acc = app_b1[j];
            for (int d = 0; d < DIM; ++d) acc += e[d] * app_w1[d * DIM + j];
            tt[j] = fmaxf(acc, 0.f);
        }
        for (int d = 0; d < DIM; ++d) {
            float acc = app_b2[d];
            for (int j = 0; j < DIM; ++j) acc += tt[j] * app_w2[j * DIM + d];
            ws_a[v * DIM + d] = acc;
        }
    }
    __syncthreads();
    if (v < VOCABN) {
        // stable rank: descending score, ties broken by lower vocab id first
        const float my = s_score[v];
        int r = 0;
        for (int u = 0; u < VOCABN; ++u) {
            if (s_score[u] > my) ++r;
            else if (s_score[u] == my && u < v) ++r;
        }
        ws_rank[r] = v;
    }
}

// ---------------------------------------------------------------------------
// Kernel B: one block per batch row. 256 threads x 16 tokens each.
//   - write scores via 6-entry LUT
//   - 6-bin histogram + stable prefix (Hillis-Steele scan of 6-vectors)
//   - thread 0: selected counts per vocab rank, pooled, classifier -> pred
//   - scatter top_idx (stored as float, indices exactly representable)
// ---------------------------------------------------------------------------
__global__ __launch_bounds__(256) void row_kernel(const int* __restrict__ x,
                                                  const float* __restrict__ ws_score,
                                                  const float* __restrict__ ws_a,
                                                  const int* __restrict__ ws_rank,
                                                  const float* __restrict__ cls_w1,
                                                  const float* __restrict__ cls_b1,
                                                  const float* __restrict__ cls_w2,
                                                  const float* __restrict__ cls_b2,
                                                  float* __restrict__ out_pred,
                                                  float* __restrict__ out_topidx,
                                                  float* __restrict__ out_scores) {
    const int b = blockIdx.x;
    const int t = threadIdx.x;

    __shared__ float s_score[VOCABN];
    __shared__ float s_a[VOCABN * DIM];
    __shared__ int s_rank[VOCABN];
    __shared__ int s_scan[256][VOCABN];
    __shared__ int s_sel[VOCABN];
    __shared__ int s_base[VOCABN];

    if (t < VOCABN) { s_score[t] = ws_score[t]; s_rank[t] = ws_rank[t]; }
    if (t < VOCABN * DIM) s_a[t] = ws_a[t];
    __syncthreads();

    // load this thread's 16 consecutive tokens (64B via 4x int4)
    int tok[16];
    const int4* xp = (const int4*)(x + (size_t)b * SEQ + t * 16);
    #pragma unroll
    for (int q = 0; q < 4; ++q) {
        int4 w = xp[q];
        tok[q * 4 + 0] = w.x; tok[q * 4 + 1] = w.y;
        tok[q * 4 + 2] = w.z; tok[q * 4 + 3] = w.w;
    }

    // scores output: LUT gather, vectorized store
    float4* sp = (float4*)(out_scores + (size_t)b * SEQ + t * 16);
    #pragma unroll
    for (int q = 0; q < 4; ++q) {
        float4 f;
        f.x = s_score[tok[q * 4 + 0]];
        f.y = s_score[tok[q * 4 + 1]];
        f.z = s_score[tok[q * 4 + 2]];
        f.w = s_score[tok[q * 4 + 3]];
        sp[q] = f;
    }

    // per-chunk histogram (static indexing keeps it in registers)
    int cnt[VOCABN];
    #pragma unroll
    for (int v = 0; v < VOCABN; ++v) {
        int c = 0;
        #pragma unroll
        for (int i = 0; i < 16; ++i) c += (tok[i] == v) ? 1 : 0;
        cnt[v] = c;
        s_scan[t][v] = c;
    }
    __syncthreads();

    // inclusive Hillis-Steele scan over 256 threads, 6-vector payload
    for (int off = 1; off < 256; off <<= 1) {
        int tmp[VOCABN];
        if (t >= off) {
            #pragma unroll
            for (int v = 0; v < VOCABN; ++v) tmp[v] = s_scan[t - off][v];
        }
        __syncthreads();
        if (t >= off) {
            #pragma unroll
            for (int v = 0; v < VOCABN; ++v) s_scan[t][v] += tmp[v];
        }
        __syncthreads();
    }

    int excl[VOCABN];
    #pragma unroll
    for (int v = 0; v < VOCABN; ++v) excl[v] = s_scan[t][v] - cnt[v];

    if (t == 0) {
        // selected count + output base per vocab, in score-rank order
        int rem = KSEL;
        for (int r = 0; r < VOCABN; ++r) {
            const int v = s_rank[r];
            const int tot = s_scan[255][v];
            const int take = tot < rem ? tot : rem;
            s_base[v] = KSEL - rem;
            s_sel[v] = take;
            rem -= take;
        }
        // pooled = (sum_v selcnt_v * a_v) / K ; classifier -> pred
        float pooled[DIM];
        for (int d = 0; d < DIM; ++d) {
            float acc = 0.f;
            for (int v = 0; v < VOCABN; ++v) acc += (float)s_sel[v] * s_a[v * DIM + d];
            pooled[d] = acc / (float)KSEL;
        }
        float c[DIM / 2];
        for (int j = 0; j < DIM / 2; ++j) {
            float acc = cls_b1[j];
            for (int d = 0; d < DIM; ++d) acc += pooled[d] * cls_w1[d * (DIM / 2) + j];
            c[j] = fmaxf(acc, 0.f);
        }
        float z = cls_b2[0];
        for (int j = 0; j < DIM / 2; ++j) z += c[j] * cls_w2[j];
        out_pred[b] = 1.f / (1.f + expf(-z));
    }
    __syncthreads();

    // scatter selected indices: per vocab region, ascending token index order.
    #pragma unroll
    for (int v = 0; v < VOCABN; ++v) {
        int p = excl[v];
        const int sel = s_sel[v];
        const int bs = s_base[v];
        #pragma unroll
        for (int i = 0; i < 16; ++i) {
            if (tok[i] == v) {
                if (p < sel) out_topidx[(size_t)b * KSEL + bs + p] = (float)(t * 16 + i);
                ++p;
            }
        }
    }
}

extern "C" void kernel_launch(void* const* d_in, const int* in_sizes, int n_in,
                              void* d_out, int out_size, void* d_ws, size_t ws_size,
                              hipStream_t stream) {
    const int*   x      = (const int*)  d_in[0];
    const float* emb    = (const float*)d_in[1];
    const float* sel_w1 = (const float*)d_in[2];
    const float* sel_b1 = (const float*)d_in[3];
    const float* sel_w2 = (const float*)d_in[4];
    const float* sel_b2 = (const float*)d_in[5];
    const float* app_w1 = (const float*)d_in[6];
    const float* app_b1 = (const float*)d_in[7];
    const float* app_w2 = (const float*)d_in[8];
    const float* app_b2 = (const float*)d_in[9];
    const float* cls_w1 = (const float*)d_in[10];
    const float* cls_b1 = (const float*)d_in[11];
    const float* cls_w2 = (const float*)d_in[12];
    const float* cls_b2 = (const float*)d_in[13];

    float* out = (float*)d_out;
    float* out_pred   = out;                         // [256]
    float* out_topidx = out + BATCH;                 // [256*614] stored as float
    float* out_scores = out + BATCH + BATCH * KSEL;  // [256*4096]

    float* wsf      = (float*)d_ws;
    float* ws_score = wsf;                           // 6 floats
    float* ws_a     = wsf + 8;                       // 192 floats
    int*   ws_rank  = (int*)(wsf + 8 + VOCABN * DIM);// 6 ints

    precompute_kernel<<<1, 64, 0, stream>>>(emb, sel_w1, sel_b1, sel_w2, sel_b2,
                                            app_w1, app_b1, app_w2, app_b2,
                                            ws_score, ws_a, ws_rank);
    row_kernel<<<BATCH, 256, 0, stream>>>(x, ws_score, ws_a, ws_rank,
                                          cls_w1, cls_b1, cls_w2, cls_b2,
                                          out_pred, out_topidx, out_scores);
}

// Round 2
// 91.478 us; speedup vs baseline: 2.4202x; 2.4202x over previous
//
#include <hip/hip_runtime.h>
#include <math.h>

#define VOCABN 6
#define DIM 32
#define PADI 5
#define BATCH 256
#define SEQ 4096
#define KSEL 614   // int(4096 * 0.15)

// One block per batch row; each block redundantly does the tiny per-vocab
// precompute (6 MLPs over a 13.5 KB weight set staged in LDS) — this removes
// the 124 us single-wave precompute kernel (latency-bound scalar loads).
__global__ __launch_bounds__(256) void fused_row_kernel(
    const int* __restrict__ x,
    const float* __restrict__ emb,
    const float* __restrict__ sel_w1, const float* __restrict__ sel_b1,
    const float* __restrict__ sel_w2, const float* __restrict__ sel_b2,
    const float* __restrict__ app_w1, const float* __restrict__ app_b1,
    const float* __restrict__ app_w2, const float* __restrict__ app_b2,
    const float* __restrict__ cls_w1, const float* __restrict__ cls_b1,
    const float* __restrict__ cls_w2, const float* __restrict__ cls_b2,
    float* __restrict__ out_pred,
    float* __restrict__ out_topidx,
    float* __restrict__ out_scores) {
    const int b = blockIdx.x;
    const int t = threadIdx.x;
    const int lane = t & 63;
    const int w = t >> 6;

    // weights / activations in LDS
    __shared__ float s_emb[VOCABN * DIM];
    __shared__ float s_selw1[DIM * (DIM / 2)];   // 512
    __shared__ float s_selb1[DIM / 2], s_selw2[DIM / 2];
    __shared__ float s_appw1[DIM * DIM];         // 1024
    __shared__ float s_appb1[DIM];
    __shared__ float s_appw2[DIM * DIM];         // 1024
    __shared__ float s_appb2[DIM];
    __shared__ float s_clsw1[DIM * (DIM / 2)];   // 512
    __shared__ float s_clsb1[DIM / 2], s_clsw2[DIM / 2];
    __shared__ float s_selb2, s_clsb2v;
    __shared__ float s_selh[VOCABN * (DIM / 2)]; // 96
    __shared__ float s_ah[VOCABN * DIM];         // 192
    __shared__ float s_a[VOCABN * DIM];          // 192
    __shared__ float s_score[VOCABN];
    __shared__ int s_wtot[4][VOCABN];
    __shared__ int s_sel[VOCABN], s_base[VOCABN];
    __shared__ float s_pooled[DIM], s_c[DIM / 2];

    // --- issue the token load first (HBM latency overlaps weight staging) ---
    int tok[16];
    const int4* xp = (const int4*)(x + (size_t)b * SEQ + t * 16);
    int4 tw0 = xp[0], tw1 = xp[1], tw2 = xp[2], tw3 = xp[3];

    // --- cooperative coalesced weight staging ---
    if (t < VOCABN * DIM) s_emb[t] = (t >= PADI * DIM) ? 0.f : emb[t];
    for (int i = t; i < 512; i += 256) { s_selw1[i] = sel_w1[i]; s_clsw1[i] = cls_w1[i]; }
    for (int i = t; i < 1024; i += 256) { s_appw1[i] = app_w1[i]; s_appw2[i] = app_w2[i]; }
    if (t < 16) { s_selb1[t] = sel_b1[t]; s_selw2[t] = sel_w2[t];
                  s_clsb1[t] = cls_b1[t]; s_clsw2[t] = cls_w2[t]; }
    if (t < 32) { s_appb1[t] = app_b1[t]; s_appb2[t] = app_b2[t]; }
    if (t == 0) { s_selb2 = sel_b2[0]; s_clsb2v = cls_b2[0]; }

    tok[0] = tw0.x; tok[1] = tw0.y; tok[2] = tw0.z; tok[3] = tw0.w;
    tok[4] = tw1.x; tok[5] = tw1.y; tok[6] = tw1.z; tok[7] = tw1.w;
    tok[8] = tw2.x; tok[9] = tw2.y; tok[10] = tw2.z; tok[11] = tw2.w;
    tok[12] = tw3.x; tok[13] = tw3.y; tok[14] = tw3.z; tok[15] = tw3.w;
    __syncthreads();

    // --- phase A: selector hidden layer (96 outputs) ---
    if (t < VOCABN * (DIM / 2)) {
        const int v = t >> 4, j = t & 15;
        float acc = s_selb1[j];
        #pragma unroll
        for (int d = 0; d < DIM; ++d) acc += s_emb[v * DIM + d] * s_selw1[d * (DIM / 2) + j];
        s_selh[t] = fmaxf(acc, 0.f);
    }
    __syncthreads();

    // --- phase B: approximator hidden (192) + selector logits (6) ---
    if (t < VOCABN * DIM) {
        const int v = t >> 5, j = t & 31;
        float acc = s_appb1[j];
        #pragma unroll
        for (int d = 0; d < DIM; ++d) acc += s_emb[v * DIM + d] * s_appw1[d * DIM + j];
        s_ah[t] = fmaxf(acc, 0.f);
    } else if (t < VOCABN * DIM + VOCABN) {
        const int v = t - VOCABN * DIM;
        float z = s_selb2;
        #pragma unroll
        for (int j = 0; j < DIM / 2; ++j) z += s_selh[v * (DIM / 2) + j] * s_selw2[j];
        s_score[v] = 1.f / (1.f + expf(-z));
    }
    __syncthreads();

    // --- phase C: approximator output (192), scores write, histogram + wave scan ---
    if (t < VOCABN * DIM) {
        const int v = t >> 5, d = t & 31;
        float acc = s_appb2[d];
        #pragma unroll
        for (int j = 0; j < DIM; ++j) acc += s_ah[v * DIM + j] * s_appw2[j * DIM + d];
        s_a[t] = acc;
    }

    // scores output via 6-entry LUT, vectorized store
    {
        float4* sp = (float4*)(out_scores + (size_t)b * SEQ + t * 16);
        #pragma unroll
        for (int q = 0; q < 4; ++q) {
            float4 f;
            f.x = s_score[tok[q * 4 + 0]];
            f.y = s_score[tok[q * 4 + 1]];
            f.z = s_score[tok[q * 4 + 2]];
            f.w = s_score[tok[q * 4 + 3]];
            sp[q] = f;
        }
    }

    // per-thread 6-bin histogram of its 16 tokens
    int cnt[VOCABN], val[VOCABN];
    #pragma unroll
    for (int v = 0; v < VOCABN; ++v) {
        int c = 0;
        #pragma unroll
        for (int i = 0; i < 16; ++i) c += (tok[i] == v) ? 1 : 0;
        cnt[v] = c; val[v] = c;
    }
    // intra-wave inclusive scan (shfl_up, 6 steps x 6 vocab)
    for (int off = 1; off < 64; off <<= 1) {
        #pragma unroll
        for (int v = 0; v < VOCABN; ++v) {
            int up = __shfl_up(val[v], off, 64);
            if (lane >= off) val[v] += up;
        }
    }
    if (lane == 63) {
        #pragma unroll
        for (int v = 0; v < VOCABN; ++v) s_wtot[w][v] = val[v];
    }
    __syncthreads();

    // exclusive prefix for this thread = wave prefix + intra-wave exclusive
    int excl[VOCABN];
    #pragma unroll
    for (int v = 0; v < VOCABN; ++v) {
        int pre = 0;
        for (int ww = 0; ww < 4; ++ww) pre += (ww < w) ? s_wtot[ww][v] : 0;
        excl[v] = pre + val[v] - cnt[v];
    }

    if (t == 0) {
        // stable rank of vocab by score desc (tie: lower id first), then take
        int rank[VOCABN];
        #pragma unroll
        for (int v = 0; v < VOCABN; ++v) {
            const float my = s_score[v];
            int r = 0;
            for (int u = 0; u < VOCABN; ++u) {
                if (s_score[u] > my) ++r;
                else if (s_score[u] == my && u < v) ++r;
            }
            rank[r] = v;
        }
        int rem = KSEL;
        for (int r = 0; r < VOCABN; ++r) {
            const int v = rank[r];
            const int tot = s_wtot[0][v] + s_wtot[1][v] + s_wtot[2][v] + s_wtot[3][v];
            const int take = tot < rem ? tot : rem;
            s_base[v] = KSEL - rem;
            s_sel[v] = take;
            rem -= take;
        }
    }
    __syncthreads();

    // scatter selected indices (stored as float; ints < 4096 exact)
    #pragma unroll
    for (int v = 0; v < VOCABN; ++v) {
        int p = excl[v];
        const int sel = s_sel[v];
        const int bs = s_base[v];
        #pragma unroll
        for (int i = 0; i < 16; ++i) {
            if (tok[i] == v) {
                if (p < sel) out_topidx[(size_t)b * KSEL + bs + p] = (float)(t * 16 + i);
                ++p;
            }
        }
    }

    // classifier: pooled (32 threads) -> hidden (16 threads) -> pred (1)
    if (t < DIM) {
        float acc = 0.f;
        #pragma unroll
        for (int v = 0; v < VOCABN; ++v) acc += (float)s_sel[v] * s_a[v * DIM + t];
        s_pooled[t] = acc / (float)KSEL;
    }
    __syncthreads();
    if (t < DIM / 2) {
        float acc = s_clsb1[t];
        #pragma unroll
        for (int d = 0; d < DIM; ++d) acc += s_pooled[d] * s_clsw1[d * (DIM / 2) + t];
        s_c[t] = fmaxf(acc, 0.f);
    }
    __syncthreads();
    if (t == 0) {
        float z = s_clsb2v;
        #pragma unroll
        for (int j = 0; j < DIM / 2; ++j) z += s_c[j] * s_clsw2[j];
        out_pred[b] = 1.f / (1.f + expf(-z));
    }
}

extern "C" void kernel_launch(void* const* d_in, const int* in_sizes, int n_in,
                              void* d_out, int out_size, void* d_ws, size_t ws_size,
                              hipStream_t stream) {
    const int*   x      = (const int*)  d_in[0];
    const float* emb    = (const float*)d_in[1];
    const float* sel_w1 = (const float*)d_in[2];
    const float* sel_b1 = (const float*)d_in[3];
    const float* sel_w2 = (const float*)d_in[4];
    const float* sel_b2 = (const float*)d_in[5];
    const float* app_w1 = (const float*)d_in[6];
    const float* app_b1 = (const float*)d_in[7];
    const float* app_w2 = (const float*)d_in[8];
    const float* app_b2 = (const float*)d_in[9];
    const float* cls_w1 = (const float*)d_in[10];
    const float* cls_b1 = (const float*)d_in[11];
    const float* cls_w2 = (const float*)d_in[12];
    const float* cls_b2 = (const float*)d_in[13];

    float* out = (float*)d_out;
    float* out_pred   = out;                         // [256]
    float* out_topidx = out + BATCH;                 // [256*614] stored as float
    float* out_scores = out + BATCH + BATCH * KSEL;  // [256*4096]

    fused_row_kernel<<<BATCH, 256, 0, stream>>>(
        x, emb, sel_w1, sel_b1, sel_w2, sel_b2,
        app_w1, app_b1, app_w2, app_b2,
        cls_w1, cls_b1, cls_w2, cls_b2,
        out_pred, out_topidx, out_scores);
}

// Round 3
// 90.142 us; speedup vs baseline: 2.4561x; 1.0148x over previous
//
#include <hip/hip_runtime.h>
#include <math.h>

#define VOCABN 6
#define DIM 32
#define PADI 5
#define BATCH 256
#define SEQ 4096
#define KSEL 614   // int(4096 * 0.15)

// One block per batch row, 1024 threads (16 waves -> 4 waves/SIMD for latency
// hiding; R1's 256-thread version ran 1 wave/SIMD, fully latency-exposed).
// Selector MLP lives in wave 0 with shfl reductions so the score LUT is ready
// after a single barrier; approximator runs on a disjoint thread range.
__global__ __launch_bounds__(1024) void fused_row_kernel(
    const int* __restrict__ x,
    const float* __restrict__ emb,
    const float* __restrict__ sel_w1, const float* __restrict__ sel_b1,
    const float* __restrict__ sel_w2, const float* __restrict__ sel_b2,
    const float* __restrict__ app_w1, const float* __restrict__ app_b1,
    const float* __restrict__ app_w2, const float* __restrict__ app_b2,
    const float* __restrict__ cls_w1, const float* __restrict__ cls_b1,
    const float* __restrict__ cls_w2, const float* __restrict__ cls_b2,
    float* __restrict__ out_pred,
    float* __restrict__ out_topidx,
    float* __restrict__ out_scores) {
    const int b = blockIdx.x;
    const int t = threadIdx.x;
    const int lane = t & 63;
    const int w = t >> 6;          // 16 waves

    __shared__ float s_emb[VOCABN * DIM];        // 192
    __shared__ float s_selw1[DIM * (DIM / 2)];   // 512
    __shared__ float s_selb1[DIM / 2], s_selw2[DIM / 2];
    __shared__ float s_appw1[DIM * DIM];         // 1024
    __shared__ float s_appb1[DIM];
    __shared__ float s_appw2[DIM * DIM];         // 1024
    __shared__ float s_appb2[DIM];
    __shared__ float s_clsw1[DIM * (DIM / 2)];   // 512
    __shared__ float s_clsb1[DIM / 2], s_clsw2[DIM / 2];
    __shared__ float s_selb2, s_clsb2v;
    __shared__ float s_ah[VOCABN * DIM];         // 192
    __shared__ float s_a[VOCABN * DIM];          // 192
    __shared__ float s_score[VOCABN];
    __shared__ int s_wtot[16][VOCABN];
    __shared__ int s_sel[VOCABN], s_base[VOCABN];
    __shared__ float s_pooled[DIM], s_c[DIM / 2];

    // issue the token load first so HBM/L3 latency overlaps weight staging
    const int4 tw = *(const int4*)(x + (size_t)b * SEQ + t * 4);

    // cooperative coalesced weight staging (~3-4 loads/thread)
    if (t < VOCABN * DIM) s_emb[t] = (t >= PADI * DIM) ? 0.f : emb[t];
    if (t < 512) s_selw1[t] = sel_w1[t];
    else if (t < 1024) s_clsw1[t - 512] = cls_w1[t - 512];
    s_appw1[t] = app_w1[t];
    s_appw2[t] = app_w2[t];
    if (t >= 192 && t < 208) { int i = t - 192; s_selb1[i] = sel_b1[i]; s_selw2[i] = sel_w2[i]; }
    else if (t >= 208 && t < 224) { int i = t - 208; s_clsb1[i] = cls_b1[i]; s_clsw2[i] = cls_w2[i]; }
    else if (t >= 224 && t < 256) { int i = t - 224; s_appb1[i] = app_b1[i]; s_appb2[i] = app_b2[i]; }
    else if (t == 256) s_selb2 = sel_b2[0];
    else if (t == 257) s_clsb2v = cls_b2[0];

    int tok[4];
    tok[0] = tw.x; tok[1] = tw.y; tok[2] = tw.z; tok[3] = tw.w;
    __syncthreads();

    // --- P1: selector MLP fully inside wave 0 (lanes 0..47, shfl reduce);
    //         approximator hidden on threads 128..319 concurrently ---
    if (t < 48) {
        const int v = t >> 3, j0 = (t & 7) * 2;
        float h0 = s_selb1[j0], h1 = s_selb1[j0 + 1];
        #pragma unroll
        for (int d = 0; d < DIM; ++d) {
            const float e = s_emb[v * DIM + d];
            h0 += e * s_selw1[d * (DIM / 2) + j0];
            h1 += e * s_selw1[d * (DIM / 2) + j0 + 1];
        }
        float part = fmaxf(h0, 0.f) * s_selw2[j0] + fmaxf(h1, 0.f) * s_selw2[j0 + 1];
        part += __shfl_xor(part, 1, 64);
        part += __shfl_xor(part, 2, 64);
        part += __shfl_xor(part, 4, 64);
        if ((t & 7) == 0) s_score[v] = 1.f / (1.f + expf(-(part + s_selb2)));
    } else if (t >= 128 && t < 128 + VOCABN * DIM) {
        const int i = t - 128, v = i >> 5, j = i & 31;
        float acc = s_appb1[j];
        #pragma unroll
        for (int d = 0; d < DIM; ++d) acc += s_emb[v * DIM + d] * s_appw1[d * DIM + j];
        s_ah[i] = fmaxf(acc, 0.f);
    }
    __syncthreads();

    // --- P2: scores write (all), histogram + wave scan (all), app out (128..319) ---
    if (t >= 128 && t < 128 + VOCABN * DIM) {
        const int i = t - 128, v = i >> 5, d = i & 31;
        float acc = s_appb2[d];
        #pragma unroll
        for (int j = 0; j < DIM; ++j) acc += s_ah[v * DIM + j] * s_appw2[j * DIM + d];
        s_a[i] = acc;
    }
    {
        float4 f;
        f.x = s_score[tok[0]]; f.y = s_score[tok[1]];
        f.z = s_score[tok[2]]; f.w = s_score[tok[3]];
        *(float4*)(out_scores + (size_t)b * SEQ + t * 4) = f;
    }

    int cnt[VOCABN], val[VOCABN];
    #pragma unroll
    for (int v = 0; v < VOCABN; ++v) {
        int c = 0;
        #pragma unroll
        for (int i = 0; i < 4; ++i) c += (tok[i] == v) ? 1 : 0;
        cnt[v] = c; val[v] = c;
    }
    for (int off = 1; off < 64; off <<= 1) {
        #pragma unroll
        for (int v = 0; v < VOCABN; ++v) {
            int up = __shfl_up(val[v], off, 64);
            if (lane >= off) val[v] += up;
        }
    }
    if (lane == 63) {
        #pragma unroll
        for (int v = 0; v < VOCABN; ++v) s_wtot[w][v] = val[v];
    }
    __syncthreads();

    // --- P3: cross-wave exclusive prefix; thread 0 ranks vocab + takes k ---
    int excl[VOCABN];
    #pragma unroll
    for (int v = 0; v < VOCABN; ++v) {
        int pre = 0;
        for (int ww = 0; ww < w; ++ww) pre += s_wtot[ww][v];  // LDS broadcast reads
        excl[v] = pre + val[v] - cnt[v];
    }

    if (t == 0) {
        int rank[VOCABN];
        #pragma unroll
        for (int v = 0; v < VOCABN; ++v) {
            const float my = s_score[v];
            int r = 0;
            for (int u = 0; u < VOCABN; ++u) {
                if (s_score[u] > my) ++r;
                else if (s_score[u] == my && u < v) ++r;
            }
            rank[r] = v;
        }
        int rem = KSEL;
        for (int r = 0; r < VOCABN; ++r) {
            const int v = rank[r];
            int tot = 0;
            for (int ww = 0; ww < 16; ++ww) tot += s_wtot[ww][v];
            const int take = tot < rem ? tot : rem;
            s_base[v] = KSEL - rem;
            s_sel[v] = take;
            rem -= take;
        }
    }
    __syncthreads();

    // --- P4: scatter top_idx (float; ints < 4096 exact) + classifier ---
    #pragma unroll
    for (int v = 0; v < VOCABN; ++v) {
        int p = excl[v];
        const int sel = s_sel[v];
        const int bs = s_base[v];
        #pragma unroll
        for (int i = 0; i < 4; ++i) {
            if (tok[i] == v) {
                if (p < sel) out_topidx[(size_t)b * KSEL + bs + p] = (float)(t * 4 + i);
                ++p;
            }
        }
    }

    if (t < DIM) {
        float acc = 0.f;
        #pragma unroll
        for (int v = 0; v < VOCABN; ++v) acc += (float)s_sel[v] * s_a[v * DIM + t];
        s_pooled[t] = acc / (float)KSEL;
    }
    __syncthreads();
    if (t < DIM / 2) {
        float acc = s_clsb1[t];
        #pragma unroll
        for (int d = 0; d < DIM; ++d) acc += s_pooled[d] * s_clsw1[d * (DIM / 2) + t];
        s_c[t] = fmaxf(acc, 0.f);
    }
    __syncthreads();
    if (t == 0) {
        float z = s_clsb2v;
        #pragma unroll
        for (int j = 0; j < DIM / 2; ++j) z += s_c[j] * s_clsw2[j];
        out_pred[b] = 1.f / (1.f + expf(-z));
    }
}

extern "C" void kernel_launch(void* const* d_in, const int* in_sizes, int n_in,
                              void* d_out, int out_size, void* d_ws, size_t ws_size,
                              hipStream_t stream) {
    const int*   x      = (const int*)  d_in[0];
    const float* emb    = (const float*)d_in[1];
    const float* sel_w1 = (const float*)d_in[2];
    const float* sel_b1 = (const float*)d_in[3];
    const float* sel_w2 = (const float*)d_in[4];
    const float* sel_b2 = (const float*)d_in[5];
    const float* app_w1 = (const float*)d_in[6];
    const float* app_b1 = (const float*)d_in[7];
    const float* app_w2 = (const float*)d_in[8];
    const float* app_b2 = (const float*)d_in[9];
    const float* cls_w1 = (const float*)d_in[10];
    const float* cls_b1 = (const float*)d_in[11];
    const float* cls_w2 = (const float*)d_in[12];
    const float* cls_b2 = (const float*)d_in[13];

    float* out = (float*)d_out;
    float* out_pred   = out;                         // [256]
    float* out_topidx = out + BATCH;                 // [256*614] stored as float
    float* out_scores = out + BATCH + BATCH * KSEL;  // [256*4096]

    fused_row_kernel<<<BATCH, 1024, 0, stream>>>(
        x, emb, sel_w1, sel_b1, sel_w2, sel_b2,
        app_w1, app_b1, app_w2, app_b2,
        cls_w1, cls_b1, cls_w2, cls_b2,
        out_pred, out_topidx, out_scores);
}